// Round 2
// baseline (358.121 us; speedup 1.0000x reference)
//
#include <hip/hip_runtime.h>
#include <hip/hip_bf16.h>
#include <stdint.h>

#define B_ 4
#define S_ 2048
#define H_ 1024
#define NH_ 16
#define DH_ 64
#define M_ (B_*S_)   // 8192

typedef __bf16 bf16x8 __attribute__((ext_vector_type(8)));
typedef float f32x4 __attribute__((ext_vector_type(4)));

static_assert(sizeof(__bf16) == 2, "bf16 size");

// ---------------------------------------------------------------- cast ----
__global__ __launch_bounds__(256)
void cast_f32_bf16(const float* __restrict__ src, __bf16* __restrict__ dst, int n)
{
    int i = (blockIdx.x * 256 + threadIdx.x) * 8;
    if (i < n) {
        float4 a = *(const float4*)(src + i);
        float4 b = *(const float4*)(src + i + 4);
        bf16x8 o;
        o[0] = (__bf16)a.x; o[1] = (__bf16)a.y; o[2] = (__bf16)a.z; o[3] = (__bf16)a.w;
        o[4] = (__bf16)b.x; o[5] = (__bf16)b.y; o[6] = (__bf16)b.z; o[7] = (__bf16)b.w;
        *(bf16x8*)(dst + i) = o;
    }
}

// ---------------------------------------------------------------- GEMM ----
// C[M,N] = A[M,K] @ Bw[N,K]^T + bias  (torch Linear). bf16 in, fp32 acc.
template<int EPI>
__global__ __launch_bounds__(256)
void gemm_bt(const __bf16* __restrict__ A, const __bf16* __restrict__ Bw,
             const float* __restrict__ bias, const float* __restrict__ resid,
             void* __restrict__ outp, int Mdim, int Ndim, int Kdim)
{
    __shared__ __align__(16) __bf16 As[128][72];
    __shared__ __align__(16) __bf16 Bs[128][72];

    const int tid  = threadIdx.x;
    const int lane = tid & 63, wv = tid >> 6;
    const int wr = wv >> 1, wc = wv & 1;           // 2x2 wave grid, 64x64 each
    const int m0 = blockIdx.y * 128, n0 = blockIdx.x * 128;
    const int rl = lane & 15, rg = lane >> 4;

    f32x4 acc[4][4] = {};

    const int sr = tid >> 3;            // staging row (0..31), 4 passes
    const int sc = (tid & 7) * 8;       // staging col (bf16 elements)

    for (int k0 = 0; k0 < Kdim; k0 += 64) {
#pragma unroll
        for (int p = 0; p < 4; ++p) {
            int r = sr + p * 32;
            *(bf16x8*)(&As[r][sc]) = *(const bf16x8*)(A  + (size_t)(m0 + r) * Kdim + k0 + sc);
            *(bf16x8*)(&Bs[r][sc]) = *(const bf16x8*)(Bw + (size_t)(n0 + r) * Kdim + k0 + sc);
        }
        __syncthreads();
#pragma unroll
        for (int ks = 0; ks < 2; ++ks) {
            const int kb = ks * 32 + rg * 8;       // element offset in LDS row
            bf16x8 af[4], bfr[4];
#pragma unroll
            for (int m = 0; m < 4; ++m) af[m]  = *(const bf16x8*)(&As[wr * 64 + m * 16 + rl][kb]);
#pragma unroll
            for (int n = 0; n < 4; ++n) bfr[n] = *(const bf16x8*)(&Bs[wc * 64 + n * 16 + rl][kb]);
#pragma unroll
            for (int m = 0; m < 4; ++m)
#pragma unroll
                for (int n = 0; n < 4; ++n)
                    acc[m][n] = __builtin_amdgcn_mfma_f32_16x16x32_bf16(af[m], bfr[n], acc[m][n], 0, 0, 0);
        }
        __syncthreads();
    }

    // epilogue: C/D layout col = lane&15, row = (lane>>4)*4 + reg   [m89]
#pragma unroll
    for (int m = 0; m < 4; ++m) {
#pragma unroll
        for (int n = 0; n < 4; ++n) {
            const int col = n0 + wc * 64 + n * 16 + rl;
            const float bv = bias[col];
#pragma unroll
            for (int r = 0; r < 4; ++r) {
                const int row = m0 + wr * 64 + m * 16 + rg * 4 + r;
                const size_t idx = (size_t)row * Ndim + col;
                float v = acc[m][n][r] + bv;
                if (EPI == 0) {
                    ((__bf16*)outp)[idx] = (__bf16)v;
                } else {
                    ((float*)outp)[idx] = v + resid[idx];
                }
            }
        }
    }
}

// ---------------------------------------------------------- V transpose ----
// v [B,S,H] bf16 -> vt [B,NH,DH,S] bf16
__global__ __launch_bounds__(256)
void transpose_v(const __bf16* __restrict__ v, __bf16* __restrict__ vt)
{
    __shared__ __align__(16) __bf16 T[64][72];
    const int s0 = blockIdx.x * 64;
    const int bh = blockIdx.y;
    const int b = bh / NH_, h = bh % NH_;
    const int tid = threadIdx.x;
    const int r  = tid >> 2;            // 0..63
    const int c  = (tid & 3) * 16;      // 0,16,32,48

#pragma unroll
    for (int i = 0; i < 2; ++i)
        *(bf16x8*)(&T[r][c + i * 8]) =
            *(const bf16x8*)(v + (size_t)(b * S_ + s0 + r) * H_ + h * DH_ + c + i * 8);
    __syncthreads();

    bf16x8 o0, o1;
#pragma unroll
    for (int i = 0; i < 8; ++i) { o0[i] = T[c + i][r]; o1[i] = T[c + 8 + i][r]; }
    size_t obase = ((size_t)(b * NH_ + h) * DH_ + r) * S_ + s0 + c;
    *(bf16x8*)(vt + obase)     = o0;
    *(bf16x8*)(vt + obase + 8) = o1;
}

// ------------------------------------------------------------ attention ----
// Swapped QK^T: S^T = mfma(K, Q). Lane (rl,rg) holds, per q-tile qm,
// S[key = kt*16+rg*4+r][q = qm*16+rl]. Softmax reduce: 32 in-lane + 2 shfl.
// P redistributed to PV A-fragments by 8 shfl per 32-key block (no P LDS).
// Ks/Vs linear + XOR swizzle (byte ^= (row&7)<<4): bank-balanced b128 reads.
__device__ __forceinline__ uint32_t pack_bf16(float lo, float hi)
{
    union { __bf16 h[2]; uint32_t u; } t;
    t.h[0] = (__bf16)lo; t.h[1] = (__bf16)hi;
    return t.u;
}

__global__ __launch_bounds__(256, 3)
void attn_fwd(const __bf16* __restrict__ q, const __bf16* __restrict__ k,
              const __bf16* __restrict__ vt, const float* __restrict__ mask,
              __bf16* __restrict__ ctx)
{
    __shared__ __align__(16) char Ks[128 * 128];   // 128 keys x 64 dh bf16, swizzled
    __shared__ __align__(16) char Vs[64 * 256];    // 64 dh x 128 keys bf16, swizzled

    const int qt0 = blockIdx.x * 128;
    const int h = blockIdx.y, b = blockIdx.z;
    const int tid = threadIdx.x, lane = tid & 63, wv = tid >> 6;
    const int rl = lane & 15, rg = lane >> 4;
    const int swz = (rl & 7) << 4;
    const float* mbase = mask + (size_t)b * S_;

    // Q as B-fragment (col = q = rl, k-elems dh = rg*8+j)
    bf16x8 qf[2][2];
#pragma unroll
    for (int qm = 0; qm < 2; ++qm)
#pragma unroll
        for (int ks = 0; ks < 2; ++ks)
            qf[qm][ks] = *(const bf16x8*)(q + (size_t)(b * S_ + qt0 + wv * 32 + qm * 16 + rl) * H_
                                            + h * DH_ + ks * 32 + rg * 8);

    f32x4 cacc[2][4] = {};
    float mrow[2] = {-1e30f, -1e30f}, lrow[2] = {0.f, 0.f};

    const int skr = tid >> 3, skc = (tid & 7) * 16;    // K staging: row, byte-chunk
    const int svr = tid >> 4, svc = (tid & 15) * 16;   // V staging
    const int srcA = rl + 16 * ((2 * rg) & 3);
    const int srcB = rl + 16 * ((2 * rg + 1) & 3);
    const bool losel = rg < 2;

    for (int kt0 = 0; kt0 < S_; kt0 += 128) {
        // ---- stage K (16 KB) and V^T (16 KB), XOR-swizzled rows
#pragma unroll
        for (int p = 0; p < 4; ++p) {
            int r = skr + p * 32;
            *(bf16x8*)(Ks + r * 128 + (skc ^ ((r & 7) << 4))) =
                *(const bf16x8*)(k + (size_t)(b * S_ + kt0 + r) * H_ + h * DH_ + (tid & 7) * 8);
        }
#pragma unroll
        for (int p = 0; p < 4; ++p) {
            int r = svr + p * 16;
            *(bf16x8*)(Vs + r * 256 + (svc ^ ((r & 7) << 4))) =
                *(const bf16x8*)(vt + ((size_t)(b * NH_ + h) * DH_ + r) * S_ + kt0 + (tid & 15) * 8);
        }
        __syncthreads();

        // ---- S^T = K @ Q^T : sacc[kt][qm], key = kt*16+rg*4+r, q = qm*16+rl
        f32x4 sacc[8][2];
#pragma unroll
        for (int kt = 0; kt < 8; ++kt) { sacc[kt][0] = f32x4{0,0,0,0}; sacc[kt][1] = f32x4{0,0,0,0}; }
#pragma unroll
        for (int ks = 0; ks < 2; ++ks)
#pragma unroll
            for (int kt = 0; kt < 8; ++kt) {
                bf16x8 kf = *(const bf16x8*)(Ks + (kt * 16 + rl) * 128 + ((ks * 64 + rg * 16) ^ swz));
                sacc[kt][0] = __builtin_amdgcn_mfma_f32_16x16x32_bf16(kf, qf[0][ks], sacc[kt][0], 0, 0, 0);
                sacc[kt][1] = __builtin_amdgcn_mfma_f32_16x16x32_bf16(kf, qf[1][ks], sacc[kt][1], 0, 0, 0);
            }

        // ---- scale + mask + per-qm running max
        float mx0 = -1e30f, mx1 = -1e30f;
#pragma unroll
        for (int kt = 0; kt < 8; ++kt) {
            float4 m4 = *(const float4*)(mbase + kt0 + kt * 16 + rg * 4);
            float mm[4] = {m4.x, m4.y, m4.z, m4.w};
#pragma unroll
            for (int r = 0; r < 4; ++r) {
                float s0 = sacc[kt][0][r] * 0.125f + mm[r];
                float s1 = sacc[kt][1][r] * 0.125f + mm[r];
                sacc[kt][0][r] = s0; sacc[kt][1][r] = s1;
                mx0 = fmaxf(mx0, s0); mx1 = fmaxf(mx1, s1);
            }
        }

#pragma unroll
        for (int qm = 0; qm < 2; ++qm) {
            float mx = qm ? mx1 : mx0;
            mx = fmaxf(mx, __shfl_xor(mx, 16, 64));
            mx = fmaxf(mx, __shfl_xor(mx, 32, 64));
            float mnew = fmaxf(mrow[qm], mx);
            float ef = __expf(mrow[qm] - mnew);
            mrow[qm] = mnew;
            // redistribute ef to cacc-row owners (cacc row q = qm*16+rg*4+r)
            float ef4[4];
#pragma unroll
            for (int r = 0; r < 4; ++r) ef4[r] = __shfl(ef, rg * 4 + r, 64);
#pragma unroll
            for (int n = 0; n < 4; ++n)
#pragma unroll
                for (int r = 0; r < 4; ++r) cacc[qm][n][r] *= ef4[r];

            float rs = 0.f;
#pragma unroll
            for (int t = 0; t < 4; ++t) {
                // exp for keys 32t..32t+31 (this lane: rg*4+r and 16+rg*4+r)
                float p0 = __expf(sacc[2 * t][qm][0] - mnew);
                float p1 = __expf(sacc[2 * t][qm][1] - mnew);
                float p2 = __expf(sacc[2 * t][qm][2] - mnew);
                float p3 = __expf(sacc[2 * t][qm][3] - mnew);
                float q0 = __expf(sacc[2 * t + 1][qm][0] - mnew);
                float q1 = __expf(sacc[2 * t + 1][qm][1] - mnew);
                float q2 = __expf(sacc[2 * t + 1][qm][2] - mnew);
                float q3 = __expf(sacc[2 * t + 1][qm][3] - mnew);
                rs += (p0 + p1 + p2 + p3) + (q0 + q1 + q2 + q3);
                uint32_t e0 = pack_bf16(p0, p1), e1 = pack_bf16(p2, p3);
                uint32_t o0 = pack_bf16(q0, q1), o1 = pack_bf16(q2, q3);
                // gather PV A-fragment dwords: keys t*32 + rg*8 + {0..7}, q = rl
                uint32_t a0 = (uint32_t)__shfl((int)e0, srcA, 64);
                uint32_t b0 = (uint32_t)__shfl((int)o0, srcA, 64);
                uint32_t a1 = (uint32_t)__shfl((int)e1, srcA, 64);
                uint32_t b1 = (uint32_t)__shfl((int)o1, srcA, 64);
                uint32_t a2 = (uint32_t)__shfl((int)e0, srcB, 64);
                uint32_t b2 = (uint32_t)__shfl((int)o0, srcB, 64);
                uint32_t a3 = (uint32_t)__shfl((int)e1, srcB, 64);
                uint32_t b3 = (uint32_t)__shfl((int)o1, srcB, 64);
                union { uint32_t u[4]; bf16x8 v; } pa;
                pa.u[0] = losel ? a0 : b0;
                pa.u[1] = losel ? a1 : b1;
                pa.u[2] = losel ? a2 : b2;
                pa.u[3] = losel ? a3 : b3;
#pragma unroll
                for (int n = 0; n < 4; ++n) {
                    bf16x8 vb = *(const bf16x8*)(Vs + (n * 16 + rl) * 256 + ((t * 64 + rg * 16) ^ swz));
                    cacc[qm][n] = __builtin_amdgcn_mfma_f32_16x16x32_bf16(pa.v, vb, cacc[qm][n], 0, 0, 0);
                }
            }
            rs += __shfl_xor(rs, 16, 64);
            rs += __shfl_xor(rs, 32, 64);
            lrow[qm] = lrow[qm] * ef + rs;
        }
        __syncthreads();
    }

    // ---- normalize + write ctx [B,S,H] bf16
#pragma unroll
    for (int qm = 0; qm < 2; ++qm) {
        float inv = 1.f / lrow[qm];
        float inv4[4];
#pragma unroll
        for (int r = 0; r < 4; ++r) inv4[r] = __shfl(inv, rg * 4 + r, 64);
#pragma unroll
        for (int r = 0; r < 4; ++r) {
            int row = qt0 + wv * 32 + qm * 16 + rg * 4 + r;
            size_t gb = (size_t)(b * S_ + row) * H_ + h * DH_;
#pragma unroll
            for (int n = 0; n < 4; ++n)
                ctx[gb + n * 16 + rl] = (__bf16)(cacc[qm][n][r] * inv4[r]);
        }
    }
}

// ------------------------------------------------------------ layernorm ----
__global__ __launch_bounds__(256)
void ln_kernel(const float* __restrict__ x, const float* __restrict__ gamma,
               const float* __restrict__ beta, float* __restrict__ out)
{
    const int row = blockIdx.x;
    const int t = threadIdx.x;
    const float* xr = x + (size_t)row * H_;
    float4 v = *(const float4*)(xr + t * 4);
    float s  = v.x + v.y + v.z + v.w;
    float ss = v.x * v.x + v.y * v.y + v.z * v.z + v.w * v.w;
#pragma unroll
    for (int off = 1; off < 64; off <<= 1) {
        s  += __shfl_xor(s, off, 64);
        ss += __shfl_xor(ss, off, 64);
    }
    __shared__ float sb[8];
    const int wv = t >> 6, lane = t & 63;
    if (lane == 0) { sb[wv] = s; sb[4 + wv] = ss; }
    __syncthreads();
    s  = sb[0] + sb[1] + sb[2] + sb[3];
    ss = sb[4] + sb[5] + sb[6] + sb[7];
    const float mu = s * (1.f / H_);
    const float var = ss * (1.f / H_) - mu * mu;
    const float rstd = rsqrtf(var + 1e-12f);
    float4 g = *(const float4*)(gamma + t * 4);
    float4 bt = *(const float4*)(beta + t * 4);
    float4 o;
    o.x = (v.x - mu) * rstd * g.x + bt.x;
    o.y = (v.y - mu) * rstd * g.y + bt.y;
    o.z = (v.z - mu) * rstd * g.z + bt.z;
    o.w = (v.w - mu) * rstd * g.w + bt.w;
    *(float4*)(out + (size_t)row * H_ + t * 4) = o;
}

// -------------------------------------------------------------- launch ----
extern "C" void kernel_launch(void* const* d_in, const int* in_sizes, int n_in,
                              void* d_out, int out_size, void* d_ws, size_t ws_size,
                              hipStream_t stream)
{
    const float* hs    = (const float*)d_in[0];
    const float* mask  = (const float*)d_in[1];
    const float* Wq    = (const float*)d_in[2];
    const float* bq    = (const float*)d_in[3];
    const float* Wk    = (const float*)d_in[4];
    const float* bk    = (const float*)d_in[5];
    const float* Wv    = (const float*)d_in[6];
    const float* bv    = (const float*)d_in[7];
    const float* Wo    = (const float*)d_in[8];
    const float* bo    = (const float*)d_in[9];
    const float* gamma = (const float*)d_in[10];
    const float* beta  = (const float*)d_in[11];

    char* ws = (char*)d_ws;
    const size_t MB = 1ull << 20;
    __bf16* x_bf   = (__bf16*)(ws);             // 16 MB (dead after QKV GEMMs)
    __bf16* wq_bf  = (__bf16*)(ws + 16 * MB);   // 2 MB each
    __bf16* wk_bf  = (__bf16*)(ws + 18 * MB);
    __bf16* wv_bf  = (__bf16*)(ws + 20 * MB);
    __bf16* wo_bf  = (__bf16*)(ws + 22 * MB);
    __bf16* q_bf   = (__bf16*)(ws + 24 * MB);   // 16 MB
    __bf16* k_bf   = (__bf16*)(ws + 40 * MB);   // 16 MB
    __bf16* v_bf   = (__bf16*)(ws + 56 * MB);   // 16 MB
    __bf16* vt_bf  = (__bf16*)(ws + 72 * MB);   // 16 MB   (total 88 MB)
    __bf16* ctx_bf = (__bf16*)(ws);             // aliases x_bf (x dead by then)
    float*  pre    = (float*)(ws + 24 * MB);    // 32 MB, aliases q/k (dead by then)

    const int nx = M_ * H_;
    const int nw = H_ * H_;
    cast_f32_bf16<<<nx / 2048, 256, 0, stream>>>(hs, x_bf, nx);
    cast_f32_bf16<<<nw / 2048, 256, 0, stream>>>(Wq, wq_bf, nw);
    cast_f32_bf16<<<nw / 2048, 256, 0, stream>>>(Wk, wk_bf, nw);
    cast_f32_bf16<<<nw / 2048, 256, 0, stream>>>(Wv, wv_bf, nw);
    cast_f32_bf16<<<nw / 2048, 256, 0, stream>>>(Wo, wo_bf, nw);

    dim3 gg(H_ / 128, M_ / 128);
    gemm_bt<0><<<gg, 256, 0, stream>>>(x_bf, wq_bf, bq, nullptr, q_bf, M_, H_, H_);
    gemm_bt<0><<<gg, 256, 0, stream>>>(x_bf, wk_bf, bk, nullptr, k_bf, M_, H_, H_);
    gemm_bt<0><<<gg, 256, 0, stream>>>(x_bf, wv_bf, bv, nullptr, v_bf, M_, H_, H_);

    transpose_v<<<dim3(S_ / 64, B_ * NH_), 256, 0, stream>>>(v_bf, vt_bf);

    attn_fwd<<<dim3(S_ / 128, NH_, B_), 256, 0, stream>>>(q_bf, k_bf, vt_bf, mask, ctx_bf);

    gemm_bt<1><<<gg, 256, 0, stream>>>(ctx_bf, wo_bf, bo, hs, pre, M_, H_, H_);

    ln_kernel<<<M_, 256, 0, stream>>>(pre, gamma, beta, (float*)d_out);
}

// Round 3
// 318.773 us; speedup vs baseline: 1.1234x; 1.1234x over previous
//
#include <hip/hip_runtime.h>
#include <hip/hip_bf16.h>
#include <stdint.h>

#define B_ 4
#define S_ 2048
#define H_ 1024
#define NH_ 16
#define DH_ 64
#define M_ (B_*S_)   // 8192

typedef __bf16 bf16x8 __attribute__((ext_vector_type(8)));
typedef float f32x4 __attribute__((ext_vector_type(4)));
typedef short v4s __attribute__((ext_vector_type(4)));

static_assert(sizeof(__bf16) == 2, "bf16 size");

// ---------------------------------------------------------------- cast ----
__global__ __launch_bounds__(256)
void cast_f32_bf16(const float* __restrict__ src, __bf16* __restrict__ dst, int n)
{
    int i = (blockIdx.x * 256 + threadIdx.x) * 8;
    if (i < n) {
        float4 a = *(const float4*)(src + i);
        float4 b = *(const float4*)(src + i + 4);
        bf16x8 o;
        o[0] = (__bf16)a.x; o[1] = (__bf16)a.y; o[2] = (__bf16)a.z; o[3] = (__bf16)a.w;
        o[4] = (__bf16)b.x; o[5] = (__bf16)b.y; o[6] = (__bf16)b.z; o[7] = (__bf16)b.w;
        *(bf16x8*)(dst + i) = o;
    }
}

// ---------------------------------------------------------------- GEMM ----
// C[M,N] = A[M,K] @ Bw[N,K]^T + bias  (torch Linear). bf16 in, fp32 acc.
template<int EPI>
__global__ __launch_bounds__(256)
void gemm_bt(const __bf16* __restrict__ A, const __bf16* __restrict__ Bw,
             const float* __restrict__ bias, const float* __restrict__ resid,
             void* __restrict__ outp, int Mdim, int Ndim, int Kdim)
{
    __shared__ __align__(16) __bf16 As[128][72];
    __shared__ __align__(16) __bf16 Bs[128][72];

    const int tid  = threadIdx.x;
    const int lane = tid & 63, wv = tid >> 6;
    const int wr = wv >> 1, wc = wv & 1;           // 2x2 wave grid, 64x64 each
    const int m0 = blockIdx.y * 128, n0 = blockIdx.x * 128;
    const int rl = lane & 15, rg = lane >> 4;

    f32x4 acc[4][4] = {};

    const int sr = tid >> 3;            // staging row (0..31), 4 passes
    const int sc = (tid & 7) * 8;       // staging col (bf16 elements)

    for (int k0 = 0; k0 < Kdim; k0 += 64) {
#pragma unroll
        for (int p = 0; p < 4; ++p) {
            int r = sr + p * 32;
            *(bf16x8*)(&As[r][sc]) = *(const bf16x8*)(A  + (size_t)(m0 + r) * Kdim + k0 + sc);
            *(bf16x8*)(&Bs[r][sc]) = *(const bf16x8*)(Bw + (size_t)(n0 + r) * Kdim + k0 + sc);
        }
        __syncthreads();
#pragma unroll
        for (int ks = 0; ks < 2; ++ks) {
            const int kb = ks * 32 + rg * 8;       // element offset in LDS row
            bf16x8 af[4], bfr[4];
#pragma unroll
            for (int m = 0; m < 4; ++m) af[m]  = *(const bf16x8*)(&As[wr * 64 + m * 16 + rl][kb]);
#pragma unroll
            for (int n = 0; n < 4; ++n) bfr[n] = *(const bf16x8*)(&Bs[wc * 64 + n * 16 + rl][kb]);
#pragma unroll
            for (int m = 0; m < 4; ++m)
#pragma unroll
                for (int n = 0; n < 4; ++n)
                    acc[m][n] = __builtin_amdgcn_mfma_f32_16x16x32_bf16(af[m], bfr[n], acc[m][n], 0, 0, 0);
        }
        __syncthreads();
    }

    // epilogue: C/D layout col = lane&15, row = (lane>>4)*4 + reg   [m89]
#pragma unroll
    for (int m = 0; m < 4; ++m) {
#pragma unroll
        for (int n = 0; n < 4; ++n) {
            const int col = n0 + wc * 64 + n * 16 + rl;
            const float bv = bias[col];
#pragma unroll
            for (int r = 0; r < 4; ++r) {
                const int row = m0 + wr * 64 + m * 16 + rg * 4 + r;
                const size_t idx = (size_t)row * Ndim + col;
                float v = acc[m][n][r] + bv;
                if (EPI == 0) {
                    ((__bf16*)outp)[idx] = (__bf16)v;
                } else {
                    ((float*)outp)[idx] = v + resid[idx];
                }
            }
        }
    }
}

// ---------------------------------------------------------- V transpose ----
// v [B,S,H] bf16 -> vt [B,NH,DH,S] bf16
__global__ __launch_bounds__(256)
void transpose_v(const __bf16* __restrict__ v, __bf16* __restrict__ vt)
{
    __shared__ __align__(16) __bf16 T[64][72];
    const int s0 = blockIdx.x * 64;
    const int bh = blockIdx.y;
    const int b = bh / NH_, h = bh % NH_;
    const int tid = threadIdx.x;
    const int r  = tid >> 2;            // 0..63
    const int c  = (tid & 3) * 16;      // 0,16,32,48

#pragma unroll
    for (int i = 0; i < 2; ++i)
        *(bf16x8*)(&T[r][c + i * 8]) =
            *(const bf16x8*)(v + (size_t)(b * S_ + s0 + r) * H_ + h * DH_ + c + i * 8);
    __syncthreads();

    bf16x8 o0, o1;
#pragma unroll
    for (int i = 0; i < 8; ++i) { o0[i] = T[c + i][r]; o1[i] = T[c + 8 + i][r]; }
    size_t obase = ((size_t)(b * NH_ + h) * DH_ + r) * S_ + s0 + c;
    *(bf16x8*)(vt + obase)     = o0;
    *(bf16x8*)(vt + obase + 8) = o1;
}

// ------------------------------------------------------------ attention ----
// Swapped QK^T: S^T = mfma_16x16x32(K, Q) -> lane (rl,rg) holds
// P^T[key=16kt+rg*4+r][q=rl]. That IS the B-fragment of mfma_16x16x16, so
// PV is O^T = mfma_16x16x16(A=V^T, B=P^T): ZERO cross-lane redistribution.
// m/l/rescale/normalize all lane-local (lane owns q=rl); only 4 shfl_xor
// per q-tile (max & sum reduces over rg groups).
__device__ __forceinline__ uint32_t pack_bf16(float lo, float hi)
{
    union { __bf16 h[2]; uint32_t u; } t;
    t.h[0] = (__bf16)lo; t.h[1] = (__bf16)hi;
    return t.u;
}

__device__ __forceinline__ f32x4 mfma16x16x16(v4s a, v4s b, f32x4 c)
{
#if __has_builtin(__builtin_amdgcn_mfma_f32_16x16x16bf16_1k)
    return __builtin_amdgcn_mfma_f32_16x16x16bf16_1k(a, b, c, 0, 0, 0);
#else
    asm volatile("v_mfma_f32_16x16x16_bf16 %0, %1, %2, %0"
                 : "+v"(c) : "v"(a), "v"(b));
    return c;
#endif
}

__global__ __launch_bounds__(256)
void attn_fwd(const __bf16* __restrict__ q, const __bf16* __restrict__ k,
              const __bf16* __restrict__ vt, const float* __restrict__ mask,
              __bf16* __restrict__ ctx)
{
    __shared__ __align__(16) char Ks[128 * 128];   // 128 keys x 64 dh bf16, swizzled
    __shared__ __align__(16) char Vs[64 * 256];    // 64 dh x 128 keys bf16, swizzled

    const int qt0 = blockIdx.x * 128;
    const int h = blockIdx.y, b = blockIdx.z;
    const int tid = threadIdx.x, lane = tid & 63, wv = tid >> 6;
    const int rl = lane & 15, rg = lane >> 4;
    const int swz = (rl & 7) << 4;
    const float* mbase = mask + (size_t)b * S_;
    const float SC = 0.125f * 1.44269504089f;      // 1/sqrt(64) * log2(e)
    const float L2E = 1.44269504089f;

    // Q as B-fragment (col = q = rl, k-elems dh = rg*8+j)
    bf16x8 qf[2][2];
#pragma unroll
    for (int qm = 0; qm < 2; ++qm)
#pragma unroll
        for (int ks = 0; ks < 2; ++ks)
            qf[qm][ks] = *(const bf16x8*)(q + (size_t)(b * S_ + qt0 + wv * 32 + qm * 16 + rl) * H_
                                            + h * DH_ + ks * 32 + rg * 8);

    f32x4 cacc[2][4] = {};
    float mrow[2] = {-3e38f, -3e38f}, lrow[2] = {0.f, 0.f};

    const int skr = tid >> 3, skc = (tid & 7) * 16;    // K staging: row, byte-chunk
    const int svr = tid >> 4, svc = (tid & 15) * 16;   // V staging

    for (int kt0 = 0; kt0 < S_; kt0 += 128) {
        // ---- stage K (16 KB) and V^T (16 KB), XOR-swizzled rows
#pragma unroll
        for (int p = 0; p < 4; ++p) {
            int r = skr + p * 32;
            *(bf16x8*)(Ks + r * 128 + (skc ^ ((r & 7) << 4))) =
                *(const bf16x8*)(k + (size_t)(b * S_ + kt0 + r) * H_ + h * DH_ + (tid & 7) * 8);
        }
#pragma unroll
        for (int p = 0; p < 4; ++p) {
            int r = svr + p * 16;
            *(bf16x8*)(Vs + r * 256 + (svc ^ ((r & 7) << 4))) =
                *(const bf16x8*)(vt + ((size_t)(b * NH_ + h) * DH_ + r) * S_ + kt0 + (tid & 15) * 8);
        }
        __syncthreads();

#pragma unroll
        for (int qm = 0; qm < 2; ++qm) {
            // ---- S^T = K @ Q^T : key = kt*16+rg*4+r, q = qm*16+rl
            f32x4 sacc[8];
#pragma unroll
            for (int kt = 0; kt < 8; ++kt) sacc[kt] = f32x4{0, 0, 0, 0};
#pragma unroll
            for (int ks = 0; ks < 2; ++ks)
#pragma unroll
                for (int kt = 0; kt < 8; ++kt) {
                    bf16x8 kf = *(const bf16x8*)(Ks + (kt * 16 + rl) * 128 + ((ks * 64 + rg * 16) ^ swz));
                    sacc[kt] = __builtin_amdgcn_mfma_f32_16x16x32_bf16(kf, qf[qm][ks], sacc[kt], 0, 0, 0);
                }

            // ---- scale (log2 units) + mask + running max
            float mx = -3e38f;
#pragma unroll
            for (int kt = 0; kt < 8; ++kt) {
                float4 m4 = *(const float4*)(mbase + kt0 + kt * 16 + rg * 4);
                float mm[4] = {m4.x * L2E, m4.y * L2E, m4.z * L2E, m4.w * L2E};
#pragma unroll
                for (int r = 0; r < 4; ++r) {
                    float s = fmaf(sacc[kt][r], SC, mm[r]);
                    sacc[kt][r] = s;
                    mx = fmaxf(mx, s);
                }
            }
            mx = fmaxf(mx, __shfl_xor(mx, 16, 64));
            mx = fmaxf(mx, __shfl_xor(mx, 32, 64));
            float mnew = fmaxf(mrow[qm], mx);
            float ef = exp2f(mrow[qm] - mnew);
            mrow[qm] = mnew;
#pragma unroll
            for (int n = 0; n < 4; ++n)
#pragma unroll
                for (int r = 0; r < 4; ++r) cacc[qm][n][r] *= ef;

            // ---- exp2 + pack (B-frag is in-lane!) + PV via 16x16x16
            float rs = 0.f;
#pragma unroll
            for (int kt = 0; kt < 8; ++kt) {
                float p0 = exp2f(sacc[kt][0] - mnew);
                float p1 = exp2f(sacc[kt][1] - mnew);
                float p2 = exp2f(sacc[kt][2] - mnew);
                float p3 = exp2f(sacc[kt][3] - mnew);
                rs += (p0 + p1) + (p2 + p3);
                union { uint32_t u[2]; v4s v; } pk;
                pk.u[0] = pack_bf16(p0, p1);
                pk.u[1] = pack_bf16(p2, p3);
#pragma unroll
                for (int n = 0; n < 4; ++n) {
                    v4s af = *(const v4s*)(Vs + (n * 16 + rl) * 256 + ((kt * 32 + rg * 8) ^ swz));
                    cacc[qm][n] = mfma16x16x16(af, pk.v, cacc[qm][n]);
                }
            }
            rs += __shfl_xor(rs, 16, 64);
            rs += __shfl_xor(rs, 32, 64);
            lrow[qm] = lrow[qm] * ef + rs;
        }
        __syncthreads();
    }

    // ---- normalize + write ctx [B,S,H] bf16 (O^T: lane has q=rl, d=rg*4+r)
#pragma unroll
    for (int qm = 0; qm < 2; ++qm) {
        const float inv = 1.f / lrow[qm];
        const int row = qt0 + wv * 32 + qm * 16 + rl;
        __bf16* cb = ctx + (size_t)(b * S_ + row) * H_ + h * DH_;
#pragma unroll
        for (int n = 0; n < 4; ++n) {
            uint32_t u0 = pack_bf16(cacc[qm][n][0] * inv, cacc[qm][n][1] * inv);
            uint32_t u1 = pack_bf16(cacc[qm][n][2] * inv, cacc[qm][n][3] * inv);
            *(uint32_t*)(cb + n * 16 + rg * 4)     = u0;
            *(uint32_t*)(cb + n * 16 + rg * 4 + 2) = u1;
        }
    }
}

// ------------------------------------------------------------ layernorm ----
__global__ __launch_bounds__(256)
void ln_kernel(const float* __restrict__ x, const float* __restrict__ gamma,
               const float* __restrict__ beta, float* __restrict__ out)
{
    const int row = blockIdx.x;
    const int t = threadIdx.x;
    const float* xr = x + (size_t)row * H_;
    float4 v = *(const float4*)(xr + t * 4);
    float s  = v.x + v.y + v.z + v.w;
    float ss = v.x * v.x + v.y * v.y + v.z * v.z + v.w * v.w;
#pragma unroll
    for (int off = 1; off < 64; off <<= 1) {
        s  += __shfl_xor(s, off, 64);
        ss += __shfl_xor(ss, off, 64);
    }
    __shared__ float sb[8];
    const int wv = t >> 6, lane = t & 63;
    if (lane == 0) { sb[wv] = s; sb[4 + wv] = ss; }
    __syncthreads();
    s  = sb[0] + sb[1] + sb[2] + sb[3];
    ss = sb[4] + sb[5] + sb[6] + sb[7];
    const float mu = s * (1.f / H_);
    const float var = ss * (1.f / H_) - mu * mu;
    const float rstd = rsqrtf(var + 1e-12f);
    float4 g = *(const float4*)(gamma + t * 4);
    float4 bt = *(const float4*)(beta + t * 4);
    float4 o;
    o.x = (v.x - mu) * rstd * g.x + bt.x;
    o.y = (v.y - mu) * rstd * g.y + bt.y;
    o.z = (v.z - mu) * rstd * g.z + bt.z;
    o.w = (v.w - mu) * rstd * g.w + bt.w;
    *(float4*)(out + (size_t)row * H_ + t * 4) = o;
}

// -------------------------------------------------------------- launch ----
extern "C" void kernel_launch(void* const* d_in, const int* in_sizes, int n_in,
                              void* d_out, int out_size, void* d_ws, size_t ws_size,
                              hipStream_t stream)
{
    const float* hs    = (const float*)d_in[0];
    const float* mask  = (const float*)d_in[1];
    const float* Wq    = (const float*)d_in[2];
    const float* bq    = (const float*)d_in[3];
    const float* Wk    = (const float*)d_in[4];
    const float* bk    = (const float*)d_in[5];
    const float* Wv    = (const float*)d_in[6];
    const float* bv    = (const float*)d_in[7];
    const float* Wo    = (const float*)d_in[8];
    const float* bo    = (const float*)d_in[9];
    const float* gamma = (const float*)d_in[10];
    const float* beta  = (const float*)d_in[11];

    char* ws = (char*)d_ws;
    const size_t MB = 1ull << 20;
    __bf16* x_bf   = (__bf16*)(ws);             // 16 MB (dead after QKV GEMMs)
    __bf16* wq_bf  = (__bf16*)(ws + 16 * MB);   // 2 MB each
    __bf16* wk_bf  = (__bf16*)(ws + 18 * MB);
    __bf16* wv_bf  = (__bf16*)(ws + 20 * MB);
    __bf16* wo_bf  = (__bf16*)(ws + 22 * MB);
    __bf16* q_bf   = (__bf16*)(ws + 24 * MB);   // 16 MB
    __bf16* k_bf   = (__bf16*)(ws + 40 * MB);   // 16 MB
    __bf16* v_bf   = (__bf16*)(ws + 56 * MB);   // 16 MB
    __bf16* vt_bf  = (__bf16*)(ws + 72 * MB);   // 16 MB   (total 88 MB)
    __bf16* ctx_bf = (__bf16*)(ws);             // aliases x_bf (x dead by then)
    float*  pre    = (float*)(ws + 24 * MB);    // 32 MB, aliases q/k (dead by then)

    const int nx = M_ * H_;
    const int nw = H_ * H_;
    cast_f32_bf16<<<nx / 2048, 256, 0, stream>>>(hs, x_bf, nx);
    cast_f32_bf16<<<nw / 2048, 256, 0, stream>>>(Wq, wq_bf, nw);
    cast_f32_bf16<<<nw / 2048, 256, 0, stream>>>(Wk, wk_bf, nw);
    cast_f32_bf16<<<nw / 2048, 256, 0, stream>>>(Wv, wv_bf, nw);
    cast_f32_bf16<<<nw / 2048, 256, 0, stream>>>(Wo, wo_bf, nw);

    dim3 gg(H_ / 128, M_ / 128);
    gemm_bt<0><<<gg, 256, 0, stream>>>(x_bf, wq_bf, bq, nullptr, q_bf, M_, H_, H_);
    gemm_bt<0><<<gg, 256, 0, stream>>>(x_bf, wk_bf, bk, nullptr, k_bf, M_, H_, H_);
    gemm_bt<0><<<gg, 256, 0, stream>>>(x_bf, wv_bf, bv, nullptr, v_bf, M_, H_, H_);

    transpose_v<<<dim3(S_ / 64, B_ * NH_), 256, 0, stream>>>(v_bf, vt_bf);

    attn_fwd<<<dim3(S_ / 128, NH_, B_), 256, 0, stream>>>(q_bf, k_bf, vt_bf, mask, ctx_bf);

    gemm_bt<1><<<gg, 256, 0, stream>>>(ctx_bf, wo_bf, bo, hs, pre, M_, H_, H_);

    ln_kernel<<<M_, 256, 0, stream>>>(pre, gamma, beta, (float*)d_out);
}